// Round 5
// baseline (577.571 us; speedup 1.0000x reference)
//
#include <hip/hip_runtime.h>
#include <hip/hip_bf16.h>
#include <hip/hip_fp16.h>

// Codebook argmin: x (32768,512) fp32, codebook (8192,512) fp32 -> codes (32768) int32
//
// v12: v11 + acc forced into AGPRs. v9-v11 all spilled ~25 arch VGPRs in
// the K-loop (WRITE 200-240 MB scratch): the compiler kept the 128-reg
// acc chain on the ARCH side of the unified file (VGPR_Count=128 = arch
// half of the 256/wave budget at the LDS-forced 2 waves/SIMD). Empty
// asm "+a" pins (init + after each chunk) put acc in AGPRs; arch side
// then holds only af/bf/addressing (~80 peak). waves_per_eu(2,2) makes
// the 256-reg/wave budget explicit. Math unchanged (absmax 0 in v9-v11).
//
// ws layout:
//   ch8  : fp8 [8192][512]   @ 0        (4 MB)
//   xh8  : fp8 [32768][512]  @ 4 MB     (16 MB)
//   cnh  : f32 [8192]        @ 20 MB    (32 KB)
//   cand : int [32768][8]    @ 20M+32K  (1 MB)
//   part : uint4 [32][32768] @ 22 MB    (16 MB)

#define M_ROWS 32768
#define DDIM   512
#define KCODES 8192
#define NCAND  8

typedef unsigned long long u64;
typedef unsigned int u32;
typedef __attribute__((ext_vector_type(4))) float f32x4;
typedef __attribute__((ext_vector_type(8))) int v8i;

#define GL2LDS(gp, lp) __builtin_amdgcn_global_load_lds(                  \
    (const __attribute__((address_space(1))) void*)(gp),                  \
    (__attribute__((address_space(3))) void*)(lp), 16, 0, 0)

__device__ __forceinline__ u32 umin32(u32 a, u32 b) { return a < b ? a : b; }
__device__ __forceinline__ u32 umax32(u32 a, u32 b) { return a > b ? a : b; }
__device__ __forceinline__ u64 umin64(u64 a, u64 b) { return a < b ? a : b; }
__device__ __forceinline__ u32 umin3(u32 a, u32 b, u32 c) {  // fuses to v_min3_u32
  return umin32(umin32(a, b), c);
}
__device__ __forceinline__ u32 med3u(u32 a, u32 b, u32 c) {
  u32 d;
  asm("v_med3_u32 %0, %1, %2, %3" : "=v"(d) : "v"(a), "v"(b), "v"(c));
  return d;
}

// float -> order-preserving u32 (ascending); used only in rescore
__device__ __forceinline__ u32 fsort(float s) {
  u32 fb = __float_as_uint(s);
  return fb ^ (u32)(((int)fb >> 31) | 0x80000000);
}

// 8 floats -> 8 packed e4m3 bytes (uint2)
__device__ __forceinline__ uint2 pk8_fp8(float4 v0, float4 v1) {
  int lo = 0, hi = 0;
  lo = __builtin_amdgcn_cvt_pk_fp8_f32(v0.x, v0.y, lo, false);
  lo = __builtin_amdgcn_cvt_pk_fp8_f32(v0.z, v0.w, lo, true);
  hi = __builtin_amdgcn_cvt_pk_fp8_f32(v1.x, v1.y, hi, false);
  hi = __builtin_amdgcn_cvt_pk_fp8_f32(v1.z, v1.w, hi, true);
  return (uint2){(u32)lo, (u32)hi};
}

// ---------------------------------------------------------------- conv codebook
__global__ __launch_bounds__(256) void conv_codebook_kernel(
    const float* __restrict__ cb, unsigned char* __restrict__ ch8,
    float* __restrict__ cnh) {
  int wave = (blockIdx.x * 256 + threadIdx.x) >> 6;
  int lane = threadIdx.x & 63;
  if (wave >= KCODES) return;
  const float* src = cb + (size_t)wave * DDIM + lane * 8;
  float4 v0 = *(const float4*)(src);
  float4 v1 = *(const float4*)(src + 4);
  *(uint2*)(ch8 + (size_t)wave * DDIM + lane * 8) = pk8_fp8(v0, v1);
  float ss = v0.x*v0.x + v0.y*v0.y + v0.z*v0.z + v0.w*v0.w
           + v1.x*v1.x + v1.y*v1.y + v1.z*v1.z + v1.w*v1.w;
#pragma unroll
  for (int off = 32; off; off >>= 1) ss += __shfl_xor(ss, off);
  if (lane == 0) cnh[wave] = 0.5f * ss;
}

// ---------------------------------------------------------------- conv x
__global__ __launch_bounds__(256) void conv_x_kernel(
    const float* __restrict__ x, unsigned char* __restrict__ xh8) {
  size_t i = ((size_t)blockIdx.x * 256 + threadIdx.x) * 8;
  float4 v0 = *(const float4*)(x + i);
  float4 v1 = *(const float4*)(x + i + 4);
  *(uint2*)(xh8 + i) = pk8_fp8(v0, v1);
}

// LDS fragment load for K=128 MFMA: lane needs global k-bytes g*32..g*32+31
// of row `row` = granules q=g*2, g*2+1. LDS[row][slot]=global[row][slot^(row&7)]
// -> read slots (g*2)^(row&7) and that ^1. Combine two b128s into v8i.
__device__ __forceinline__ v8i ld_frag(const char* L, int row, int g) {
  const int base = row * 128;
  const int sl = ((g * 2) ^ (row & 7)) * 16;
  int4 lo = *(const int4*)&L[base + sl];
  int4 hi = *(const int4*)&L[base + (sl ^ 16)];
  v8i r;
  r[0] = lo.x; r[1] = lo.y; r[2] = lo.z; r[3] = lo.w;
  r[4] = hi.x; r[5] = hi.y; r[6] = hi.z; r[7] = hi.w;
  return r;
}

// ---------------------------------------------------------------- coarse GEMM
// Block: 512 threads = 8 waves as 2x4 (wm,wn); wave = 128x64 outputs as 8x4
// grid of 16x16x128 scaled-fp8 MFMA (scales = 1.0 -> exact e4m3 math).
// K=512 in 4 chunks of BK=128 bytes, double-buffered, depth-2 prefetch,
// counted vmcnt(8) (= one chunk's 8 GL2LDS per wave stays in flight).
__global__ __launch_bounds__(512)
__attribute__((amdgpu_waves_per_eu(2, 2)))
void coarse_kernel(
    const unsigned char* __restrict__ xh8, const unsigned char* __restrict__ ch8,
    const float* __restrict__ cnh, uint4* __restrict__ part) {
  // 131072 B: 2 x {aL(32K)+bL(32K)}; epilogue tab[256][17] uint4 (69632 B)
  // overlays (written only after all K-loop reads complete).
  __shared__ __align__(16) char smem[131072];
  uint4* tab = (uint4*)smem;

  const int tid  = threadIdx.x;
  const int lane = tid & 63;
  const int wid  = tid >> 6;
  const int wm   = wid >> 2, wn = wid & 3;
  const int g    = lane >> 4, l16 = lane & 15;

  // XCD-aware swizzle (4096 blocks, 4096%8==0 -> bijective): each XCD gets
  // a contiguous run of 512 orig-ids = 4 nblk panels (B working set 512 KB,
  // L2-resident per XCD).
  const int orig = (blockIdx.x & 7) * 512 + (blockIdx.x >> 3);
  const int mblk = orig & 127;
  const int nblk = orig >> 7;
  const int row0 = mblk * 256;
  const int col0 = nblk * 256;

  const int a_ = lane >> 3, b_ = lane & 7;
  // per-lane GL2LDS source: row +a_, granule b_^a_ of the current chunk
  const size_t gsrc = (size_t)a_ * DDIM + ((b_ ^ a_) << 4);
  const unsigned char* abase = xh8 + (size_t)row0 * DDIM + gsrc;
  const unsigned char* bbase = ch8 + (size_t)col0 * DDIM + gsrc;

// stage chunk cc (256 rows x 128 k-bytes of A and B) into buffer `buf`:
// 8 GL2LDS per wave (4 A + 4 B), wave wid covers rows [wid*32, wid*32+32)
#define STAGE(cc, buf) do {                                               \
    char* base_ = smem + (buf) * 65536;                                   \
    _Pragma("unroll")                                                     \
    for (int j = 0; j < 4; ++j) {                                         \
      const int R_ = wid * 32 + j * 8;                                    \
      const size_t off_ = (size_t)R_ * DDIM + (size_t)(cc) * 128;         \
      GL2LDS(abase + off_, base_ + R_ * 128);                             \
      GL2LDS(bbase + off_, base_ + 32768 + R_ * 128);                     \
    }                                                                     \
  } while (0)

#define WAITV(n) asm volatile("s_waitcnt vmcnt(" #n ")" ::: "memory")
#define SBAR() __builtin_amdgcn_sched_barrier(0)
#define RBAR() do {                                                       \
    __builtin_amdgcn_sched_barrier(0);                                    \
    __builtin_amdgcn_s_barrier();                                         \
    __builtin_amdgcn_sched_barrier(0);                                    \
  } while (0)

// Pin the accumulator live-ranges to the AGPR half of the unified file.
// Empty asm, zero instructions; constrains regalloc class only.
#define PIN_ACC() do {                                                    \
    _Pragma("unroll")                                                     \
    for (int tm_ = 0; tm_ < 8; ++tm_)                                     \
      _Pragma("unroll")                                                   \
      for (int tn_ = 0; tn_ < 4; ++tn_)                                   \
        asm volatile("" : "+a"(acc[tm_][tn_]));                           \
  } while (0)

// Two tm-halves with af[4] live (arch peak ~80: af 32 + bf 8 + addressing;
// acc pinned to AGPRs). bf re-read per half (+4 b128/wave/chunk).
#define COMPUTE(c) do {                                                   \
    const char* aL_ = smem + ((c) & 1) * 65536;                           \
    const char* bL_ = aL_ + 32768;                                        \
    _Pragma("unroll")                                                     \
    for (int h = 0; h < 2; ++h) {                                         \
      v8i af[4];                                                          \
      _Pragma("unroll")                                                   \
      for (int t = 0; t < 4; ++t)                                         \
        af[t] = ld_frag(aL_, wm * 128 + (h * 4 + t) * 16 + l16, g);       \
      _Pragma("unroll")                                                   \
      for (int tn = 0; tn < 4; ++tn) {                                    \
        v8i bf = ld_frag(bL_, wn * 64 + tn * 16 + l16, g);                \
        _Pragma("unroll")                                                 \
        for (int tm = 0; tm < 4; ++tm)                                    \
          acc[h * 4 + tm][tn] =                                           \
              __builtin_amdgcn_mfma_scale_f32_16x16x128_f8f6f4(           \
                  af[tm], bf, acc[h * 4 + tm][tn],                        \
                  0, 0,                     /* cbsz, blgp = fp8(e4m3) */  \
                  0, 0x7F7F7F7F,            /* opsel_a, scale_a = 1.0 */  \
                  0, 0x7F7F7F7F);           /* opsel_b, scale_b = 1.0 */  \
      }                                                                   \
    }                                                                     \
    PIN_ACC();                                                            \
  } while (0)

  // codes + half-norms for this wave's 64 columns. These 4 vmem loads mix
  // into the vmcnt stream but only ADD to each counted drain (safe for
  // every issue-order interleave: each WAITV target only needs the
  // *staging* loads older than it complete, and extras only make the
  // drain stricter).
  u32 codev[4];
  float cn[4];
#pragma unroll
  for (int tn = 0; tn < 4; ++tn) {
    codev[tn] = (u32)(col0 + wn * 64 + tn * 16 + l16);
    cn[tn] = cnh[codev[tn]];
  }

  f32x4 acc[8][4];
#pragma unroll
  for (int tm = 0; tm < 8; ++tm)
#pragma unroll
    for (int tn = 0; tn < 4; ++tn) acc[tm][tn] = (f32x4){0.f, 0.f, 0.f, 0.f};
  PIN_ACC();

  STAGE(0, 0);
  SBAR();                   // pin issue order: chunk0's 8 loads oldest
  STAGE(1, 1);
  SBAR();

  WAITV(8);  RBAR();        // chunk0 landed (chunk1 stays in flight)
  COMPUTE(0);
  RBAR();                   // all waves done reading buf0
  STAGE(2, 0);

  WAITV(8);  RBAR();        // chunk1 landed (chunk2 in flight)
  COMPUTE(1);
  RBAR();                   // all waves done reading buf1
  STAGE(3, 1);

  WAITV(8);  RBAR();        // chunk2 landed (chunk3 in flight)
  COMPUTE(2);
  // no overwrite of buf0 follows -> no barrier needed here

  WAITV(0);  RBAR();        // chunk3 landed
  COMPUTE(3);

  // ---- epilogue: 4 wn passes; keys computed LAZILY inside the pass ----
  // key = float_bits(s) & ~0x1FFF | code (s > 0 by 8-sigma margin).
  // Per (tm,r): top-3 of 4 keys via min3/med3 pair-insert:
  //   a1 = min(k0,k1); a2 = max(k0,k1);
  //   lo = min(k2,k3); hi = max(k2,k3); m = max(a1,lo); a1 = min(a1,lo);
  //   a3 = med3(a2,m,hi); a2 = min3(a2,m,hi).
  // Merge sorted {x<=y<=z} into running {m1<=m2<=m3}:
  //   a = max(m1,x); m1 = min(m1,x);
  //   b = med3(m2,a,y); m2 = min3(m2,a,y); m3 = min3(m3,b,z).
  u32 m1 = ~0u, m2 = ~0u, m3 = ~0u;
#pragma unroll
  for (int p = 0; p < 4; ++p) {
    __syncthreads();
    if (wn == p) {
#pragma unroll
      for (int tm = 0; tm < 8; ++tm)
#pragma unroll
        for (int r = 0; r < 4; ++r) {
          u32 key[4];
#pragma unroll
          for (int tn = 0; tn < 4; ++tn) {
            float s = cn[tn] - acc[tm][tn][r];
            key[tn] = (__float_as_uint(s) & 0xFFFFE000u) | codev[tn];
          }
          u32 a1 = umin32(key[0], key[1]);
          u32 a2 = umax32(key[0], key[1]);
          u32 lo = umin32(key[2], key[3]), hi = umax32(key[2], key[3]);
          u32 m  = umax32(a1, lo);
          a1 = umin32(a1, lo);
          u32 a3 = med3u(a2, m, hi);
          a2 = umin3(a2, m, hi);
          const int row = wm * 128 + tm * 16 + g * 4 + r;
          tab[row * 17 + l16] = (uint4){a1, a2, a3, 0u};
        }
    }
    __syncthreads();
    if (tid < 256) {
#pragma unroll
      for (int e = 0; e < 16; ++e) {
        uint4 v = tab[tid * 17 + e];
        u32 a = umax32(m1, v.x);
        m1 = umin32(m1, v.x);
        u32 b = med3u(m2, a, v.y);
        m2 = umin3(m2, a, v.y);
        m3 = umin3(m3, b, v.z);
      }
    }
  }

  if (tid < 256)
    part[(size_t)nblk * M_ROWS + row0 + tid] = (uint4){m1, m2, m3, 0u};
#undef COMPUTE
#undef PIN_ACC
#undef STAGE
#undef WAITV
#undef SBAR
#undef RBAR
}

// ---------------------------------------------------------------- merge: global top-8
__global__ __launch_bounds__(256) void merge_kernel(
    const uint4* __restrict__ part, int* __restrict__ cand) {
  const int row = blockIdx.x * 256 + threadIdx.x;
  u32 k[NCAND];
#pragma unroll
  for (int i = 0; i < NCAND; ++i) k[i] = ~0u;
  for (int nb = 0; nb < KCODES / 256; ++nb) {
    uint4 e = part[(size_t)nb * M_ROWS + row];
    u32 t = e.x;
#pragma unroll
    for (int i = 0; i < NCAND; ++i) { u32 mx = umax32(k[i], t); k[i] = umin32(k[i], t); t = mx; }
    t = e.y;
#pragma unroll
    for (int i = 0; i < NCAND; ++i) { u32 mx = umax32(k[i], t); k[i] = umin32(k[i], t); t = mx; }
    t = e.z;
#pragma unroll
    for (int i = 0; i < NCAND; ++i) { u32 mx = umax32(k[i], t); k[i] = umin32(k[i], t); t = mx; }
  }
#pragma unroll
  for (int i = 0; i < NCAND; ++i)
    cand[row * NCAND + i] = (int)(k[i] & 0x1FFFu);
}

// ---------------------------------------------------------------- fp32 rescore (8)
__global__ __launch_bounds__(256) void rescore_kernel(
    const float* __restrict__ x, const float* __restrict__ cb,
    const float* __restrict__ cnh, const int* __restrict__ cand,
    int* __restrict__ out) {
  int wave = (blockIdx.x * 256 + threadIdx.x) >> 6;
  int lane = threadIdx.x & 63;
  if (wave >= M_ROWS) return;
  int idx[NCAND];
#pragma unroll
  for (int j = 0; j < NCAND; ++j) idx[j] = cand[wave * NCAND + j];

  const float* xr = x + (size_t)wave * DDIM + lane * 8;
  float4 x0 = *(const float4*)(xr);
  float4 x1 = *(const float4*)(xr + 4);

  float d[NCAND];
#pragma unroll
  for (int j = 0; j < NCAND; ++j) {
    const float* c = cb + (size_t)idx[j] * DDIM + lane * 8;
    float4 a0 = *(const float4*)(c);
    float4 a1 = *(const float4*)(c + 4);
    d[j] = x0.x*a0.x + x0.y*a0.y + x0.z*a0.z + x0.w*a0.w
         + x1.x*a1.x + x1.y*a1.y + x1.z*a1.z + x1.w*a1.w;
  }
#pragma unroll
  for (int off = 32; off; off >>= 1)
#pragma unroll
    for (int j = 0; j < NCAND; ++j) d[j] += __shfl_xor(d[j], off);

  if (lane == 0) {
    u64 best = ~0ull;
#pragma unroll
    for (int j = 0; j < NCAND; ++j) {
      float s = cnh[idx[j]] - d[j];
      u64 key = ((u64)fsort(s) << 32) | (u32)idx[j];  // exact fp32 + np tie-break
      best = umin64(best, key);
    }
    out[wave] = (int)(u32)best;
  }
}

// ---------------------------------------------------------------- launch
extern "C" void kernel_launch(void* const* d_in, const int* in_sizes, int n_in,
                              void* d_out, int out_size, void* d_ws, size_t ws_size,
                              hipStream_t stream) {
  const float* x  = (const float*)d_in[0];
  const float* cb = (const float*)d_in[1];
  int* out = (int*)d_out;

  char* ws = (char*)d_ws;
  unsigned char* ch8  = (unsigned char*)(ws);
  unsigned char* xh8  = (unsigned char*)(ws + (size_t)4 * 1024 * 1024);
  float*         cnh  = (float*)(ws + (size_t)20 * 1024 * 1024);
  int*           cand = (int*)(ws + (size_t)20 * 1024 * 1024 + 32 * 1024);
  uint4*         part = (uint4*)(ws + (size_t)22 * 1024 * 1024);

  conv_codebook_kernel<<<KCODES / 4, 256, 0, stream>>>(cb, ch8, cnh);
  conv_x_kernel<<<(M_ROWS * DDIM) / (256 * 8), 256, 0, stream>>>(x, xh8);
  coarse_kernel<<<(M_ROWS / 256) * (KCODES / 256), 512, 0, stream>>>(xh8, ch8, cnh, part);
  merge_kernel<<<M_ROWS / 256, 256, 0, stream>>>(part, cand);
  rescore_kernel<<<M_ROWS / 4, 256, 0, stream>>>(x, cb, cnh, cand, out);
}

// Round 6
// 384.135 us; speedup vs baseline: 1.5036x; 1.5036x over previous
//
#include <hip/hip_runtime.h>
#include <hip/hip_bf16.h>
#include <hip/hip_fp16.h>

// Codebook argmin: x (32768,512) fp32, codebook (8192,512) fp32 -> codes (32768) int32
//
// v13: v8 geometry (proven spill-free: 128x128 tile, 256 thr, VGPR 120,
// WRITE 33 MB) + XCD-band block swizzle ONLY. v8's block order streamed
// all 16 MB of A through L3 every nblk phase -> 2.15 GB of staging at the
// ~8.5 TB/s L3 ceiling = the 252 us wall. v13 gives each XCD a contiguous
// 32-mblk band (A-band 2 MB, L2-resident all kernel) and sweeps nblk with
// mblk inner (B panel 64 KB L2-resident) -> staging served by L2.
// (v9-v12 256x256 attempts all hit an un-fixable 128-arch-VGPR spill.)
//
// ws layout:
//   ch8  : fp8 [8192][512]   @ 0        (4 MB)
//   xh8  : fp8 [32768][512]  @ 4 MB     (16 MB)
//   cnh  : f32 [8192]        @ 20 MB    (32 KB)
//   cand : int [32768][8]    @ 20M+32K  (1 MB)
//   part : uint4 [64][32768] @ 22 MB    (16 MB)

#define M_ROWS 32768
#define DDIM   512
#define KCODES 8192
#define NCAND  8

typedef unsigned long long u64;
typedef unsigned int u32;
typedef __attribute__((ext_vector_type(4))) float f32x4;
typedef __attribute__((ext_vector_type(8))) int v8i;

#define GL2LDS(gp, lp) __builtin_amdgcn_global_load_lds(                  \
    (const __attribute__((address_space(1))) void*)(gp),                  \
    (__attribute__((address_space(3))) void*)(lp), 16, 0, 0)

__device__ __forceinline__ u32 umin32(u32 a, u32 b) { return a < b ? a : b; }
__device__ __forceinline__ u32 umax32(u32 a, u32 b) { return a > b ? a : b; }
__device__ __forceinline__ u64 umin64(u64 a, u64 b) { return a < b ? a : b; }
__device__ __forceinline__ u32 umin3(u32 a, u32 b, u32 c) {  // fuses to v_min3_u32
  return umin32(umin32(a, b), c);
}
__device__ __forceinline__ u32 med3u(u32 a, u32 b, u32 c) {
  u32 d;
  asm("v_med3_u32 %0, %1, %2, %3" : "=v"(d) : "v"(a), "v"(b), "v"(c));
  return d;
}

// float -> order-preserving u32 (ascending); used only in rescore
__device__ __forceinline__ u32 fsort(float s) {
  u32 fb = __float_as_uint(s);
  return fb ^ (u32)(((int)fb >> 31) | 0x80000000);
}

// 8 floats -> 8 packed e4m3 bytes (uint2)
__device__ __forceinline__ uint2 pk8_fp8(float4 v0, float4 v1) {
  int lo = 0, hi = 0;
  lo = __builtin_amdgcn_cvt_pk_fp8_f32(v0.x, v0.y, lo, false);
  lo = __builtin_amdgcn_cvt_pk_fp8_f32(v0.z, v0.w, lo, true);
  hi = __builtin_amdgcn_cvt_pk_fp8_f32(v1.x, v1.y, hi, false);
  hi = __builtin_amdgcn_cvt_pk_fp8_f32(v1.z, v1.w, hi, true);
  return (uint2){(u32)lo, (u32)hi};
}

// ---------------------------------------------------------------- conv codebook
__global__ __launch_bounds__(256) void conv_codebook_kernel(
    const float* __restrict__ cb, unsigned char* __restrict__ ch8,
    float* __restrict__ cnh) {
  int wave = (blockIdx.x * 256 + threadIdx.x) >> 6;
  int lane = threadIdx.x & 63;
  if (wave >= KCODES) return;
  const float* src = cb + (size_t)wave * DDIM + lane * 8;
  float4 v0 = *(const float4*)(src);
  float4 v1 = *(const float4*)(src + 4);
  *(uint2*)(ch8 + (size_t)wave * DDIM + lane * 8) = pk8_fp8(v0, v1);
  float ss = v0.x*v0.x + v0.y*v0.y + v0.z*v0.z + v0.w*v0.w
           + v1.x*v1.x + v1.y*v1.y + v1.z*v1.z + v1.w*v1.w;
#pragma unroll
  for (int off = 32; off; off >>= 1) ss += __shfl_xor(ss, off);
  if (lane == 0) cnh[wave] = 0.5f * ss;
}

// ---------------------------------------------------------------- conv x
__global__ __launch_bounds__(256) void conv_x_kernel(
    const float* __restrict__ x, unsigned char* __restrict__ xh8) {
  size_t i = ((size_t)blockIdx.x * 256 + threadIdx.x) * 8;
  float4 v0 = *(const float4*)(x + i);
  float4 v1 = *(const float4*)(x + i + 4);
  *(uint2*)(xh8 + i) = pk8_fp8(v0, v1);
}

// LDS fragment load for K=128 MFMA: lane needs global k-bytes g*32..g*32+31
// of row `row` = granules q=g*2, g*2+1. LDS[row][slot]=global[row][slot^(row&7)]
// -> read slots (g*2)^(row&7) and that ^1. Combine two b128s into v8i.
__device__ __forceinline__ v8i ld_frag(const char* L, int row, int g) {
  const int base = row * 128;
  const int sl = ((g * 2) ^ (row & 7)) * 16;
  int4 lo = *(const int4*)&L[base + sl];
  int4 hi = *(const int4*)&L[base + (sl ^ 16)];
  v8i r;
  r[0] = lo.x; r[1] = lo.y; r[2] = lo.z; r[3] = lo.w;
  r[4] = hi.x; r[5] = hi.y; r[6] = hi.z; r[7] = hi.w;
  return r;
}

// ---------------------------------------------------------------- coarse GEMM
// Block: 256 threads = 4 waves as 2x2 (wm,wn); wave = 64x64 outputs as 4x4
// grid of 16x16x128 scaled-fp8 MFMA (scales = 1.0 -> exact e4m3 math).
// K=512 in 4 chunks of BK=128 bytes, double-buffered: 1 barrier / chunk,
// prefetch of chunk c+1 in flight under chunk c's 16 MFMAs.
__global__ __launch_bounds__(256) void coarse_kernel(
    const unsigned char* __restrict__ xh8, const unsigned char* __restrict__ ch8,
    const float* __restrict__ cnh, uint4* __restrict__ part) {
  // 65536 B: compute = 2 x {aL(16K)+bL(16K)}; epilogue tab[128][17] uint4
  // overlays the low 34816 B (safe: written only after post-loop barrier).
  __shared__ __align__(16) char smem[65536];
  uint4* tab = (uint4*)smem;

  const int tid  = threadIdx.x;
  const int lane = tid & 63;
  const int wid  = tid >> 6;
  const int wm   = wid >> 1, wn = wid & 1;
  const int g    = lane >> 4, l16 = lane & 15;

  // XCD-band swizzle (dispatch round-robins blockIdx across the 8 XCDs):
  // XCD x owns mblk band [x*32, x*32+32) -> A-band 2 MB stays L2-resident
  // for the whole kernel; nblk sweeps slowly (mblk inner) -> B panel 64 KB
  // L2-resident per phase. Nearly all GL2LDS staging then hits L2, not L3.
  const int xcd  = blockIdx.x & 7;
  const int lid  = blockIdx.x >> 3;          // 0..2047 within the XCD
  const int nblk = lid >> 5;                 // 0..63, slow
  const int mblk = (xcd << 5) | (lid & 31);  // band base + fast inner
  const int row0 = mblk * 128;
  const int col0 = nblk * 128;

  const int a_ = lane >> 3, b_ = lane & 7;
  // per-lane GL2LDS source: row I*8+a_, granule b_^a_ of the current chunk
  const size_t gsrc = (size_t)a_ * DDIM + ((b_ ^ a_) << 4);
  const unsigned char* abase = xh8 + (size_t)row0 * DDIM + gsrc;
  const unsigned char* bbase = ch8 + (size_t)col0 * DDIM + gsrc;

// stage chunk cc (128 k-bytes of A and B tiles) into buffer `buf`
#define STAGE(cc, buf) do {                                               \
    char* sa_ = smem + (buf) * 32768;                                     \
    _Pragma("unroll")                                                     \
    for (int j = 0; j < 4; ++j) {                                         \
      const int I_ = wid * 4 + j;                                         \
      const size_t off_ = (size_t)(I_ * 8) * DDIM + (size_t)(cc) * 128;   \
      GL2LDS(abase + off_, sa_ + I_ * 1024);                              \
      GL2LDS(bbase + off_, sa_ + 16384 + I_ * 1024);                      \
    }                                                                     \
  } while (0)

  // codes + half-norms for this wave's 64 columns; load early so the
  // global loads overlap the prologue stage.
  u32 codev[4];
  float cn[4];
#pragma unroll
  for (int tn = 0; tn < 4; ++tn) {
    codev[tn] = (u32)(col0 + wn * 64 + tn * 16 + l16);
    cn[tn] = cnh[codev[tn]];
  }

  f32x4 acc[4][4];
#pragma unroll
  for (int tm = 0; tm < 4; ++tm)
#pragma unroll
    for (int tn = 0; tn < 4; ++tn) acc[tm][tn] = (f32x4){0.f, 0.f, 0.f, 0.f};

  STAGE(0, 0);
  __syncthreads();                           // drains vmcnt(0): buf0 ready

#pragma unroll
  for (int c = 0; c < 4; ++c) {              // K chunks of 128 bytes
    if (c < 3) STAGE(c + 1, (c + 1) & 1);    // prefetch: in flight under MFMAs
    const char* aL = smem + (c & 1) * 32768;
    const char* bL = aL + 16384;

    v8i af[4];
#pragma unroll
    for (int t = 0; t < 4; ++t)
      af[t] = ld_frag(aL, wm * 64 + t * 16 + l16, g);
#pragma unroll
    for (int tn = 0; tn < 4; ++tn) {
      v8i bf = ld_frag(bL, wn * 64 + tn * 16 + l16, g);
#pragma unroll
      for (int tm = 0; tm < 4; ++tm)
        acc[tm][tn] = __builtin_amdgcn_mfma_scale_f32_16x16x128_f8f6f4(
            af[tm], bf, acc[tm][tn],
            0, 0,                     // cbsz=fp8(e4m3), blgp=fp8(e4m3)
            0, 0x7F7F7F7F,            // opsel_a, scale_a = 1.0 (E8M0 127)
            0, 0x7F7F7F7F);           // opsel_b, scale_b = 1.0
    }
    __syncthreads();   // all reads of buf[c&1] done; buf[(c+1)&1] landed
  }

  // ---- epilogue phase 1: per-lane top-3 u32 keys over 4 cols x 16 rows ----
  // key = float_bits(s) & ~0x1FFF | code. s > 0 by 8-sigma margin.
  // Pair-insertion via min3/med3: top-3 of {a1<=a2<=a3, lo<=hi} is
  //   a1' = min(a1,lo); m = max(a1,lo);
  //   a2' = min3(a2,m,hi); a3' = min(a3, med3(a2,m,hi)).
  u32 k1[16], k2[16], k3[16];
#pragma unroll
  for (int tm = 0; tm < 4; ++tm)
#pragma unroll
    for (int r = 0; r < 4; ++r) {
      const int sl = tm * 4 + r;
      u32 key[4];
#pragma unroll
      for (int tn = 0; tn < 4; ++tn) {
        float s = cn[tn] - acc[tm][tn][r];
        key[tn] = (__float_as_uint(s) & 0xFFFFE000u) | codev[tn];
      }
      // first pair into empty top-3 (keys < ~0 always: s > 0)
      u32 a1 = umin32(key[0], key[1]);
      u32 a2 = umax32(key[0], key[1]);
      u32 a3 = ~0u;
      // second pair
      {
        u32 lo = umin32(key[2], key[3]), hi = umax32(key[2], key[3]);
        u32 m  = umax32(a1, lo);
        a1 = umin32(a1, lo);
        u32 b3 = med3u(a2, m, hi);
        a2 = umin3(a2, m, hi);
        a3 = umin32(a3, b3);
      }
      k1[sl] = a1; k2[sl] = a2; k3[sl] = a3;
    }

  // ---- epilogue phase 2: LDS-table reduce, two wn passes ----
  // merge sorted {v.x<=v.y<=v.z} into running sorted {m1<=m2<=m3}:
  //   m1' = min(m1,x); a = max(m1,x);
  //   m2' = min3(m2,a,y); m3' = min3(m3, med3(m2,a,y), z).
  u32 m1 = ~0u, m2 = ~0u, m3 = ~0u;
#pragma unroll
  for (int p = 0; p < 2; ++p) {
    __syncthreads();
    if (wn == p) {
#pragma unroll
      for (int tm = 0; tm < 4; ++tm)
#pragma unroll
        for (int r = 0; r < 4; ++r) {
          const int row = wm * 64 + tm * 16 + g * 4 + r;
          const int sl = tm * 4 + r;
          tab[row * 17 + l16] = (uint4){k1[sl], k2[sl], k3[sl], 0u};
        }
    }
    __syncthreads();
    if (tid < 128) {
#pragma unroll
      for (int e = 0; e < 16; ++e) {
        uint4 v = tab[tid * 17 + e];
        u32 a = umax32(m1, v.x);
        m1 = umin32(m1, v.x);
        u32 b = med3u(m2, a, v.y);
        m2 = umin3(m2, a, v.y);
        m3 = umin3(m3, b, v.z);
      }
    }
  }

  if (tid < 128)
    part[(size_t)nblk * M_ROWS + row0 + tid] = (uint4){m1, m2, m3, 0u};
#undef STAGE
}

// ---------------------------------------------------------------- merge: global top-8
__global__ __launch_bounds__(256) void merge_kernel(
    const uint4* __restrict__ part, int* __restrict__ cand) {
  const int row = blockIdx.x * 256 + threadIdx.x;
  u32 k[NCAND];
#pragma unroll
  for (int i = 0; i < NCAND; ++i) k[i] = ~0u;
  for (int nb = 0; nb < KCODES / 128; ++nb) {
    uint4 e = part[(size_t)nb * M_ROWS + row];
    u32 t = e.x;
#pragma unroll
    for (int i = 0; i < NCAND; ++i) { u32 mx = umax32(k[i], t); k[i] = umin32(k[i], t); t = mx; }
    t = e.y;
#pragma unroll
    for (int i = 0; i < NCAND; ++i) { u32 mx = umax32(k[i], t); k[i] = umin32(k[i], t); t = mx; }
    t = e.z;
#pragma unroll
    for (int i = 0; i < NCAND; ++i) { u32 mx = umax32(k[i], t); k[i] = umin32(k[i], t); t = mx; }
  }
#pragma unroll
  for (int i = 0; i < NCAND; ++i)
    cand[row * NCAND + i] = (int)(k[i] & 0x1FFFu);
}

// ---------------------------------------------------------------- fp32 rescore (8)
__global__ __launch_bounds__(256) void rescore_kernel(
    const float* __restrict__ x, const float* __restrict__ cb,
    const float* __restrict__ cnh, const int* __restrict__ cand,
    int* __restrict__ out) {
  int wave = (blockIdx.x * 256 + threadIdx.x) >> 6;
  int lane = threadIdx.x & 63;
  if (wave >= M_ROWS) return;
  int idx[NCAND];
#pragma unroll
  for (int j = 0; j < NCAND; ++j) idx[j] = cand[wave * NCAND + j];

  const float* xr = x + (size_t)wave * DDIM + lane * 8;
  float4 x0 = *(const float4*)(xr);
  float4 x1 = *(const float4*)(xr + 4);

  float d[NCAND];
#pragma unroll
  for (int j = 0; j < NCAND; ++j) {
    const float* c = cb + (size_t)idx[j] * DDIM + lane * 8;
    float4 a0 = *(const float4*)(c);
    float4 a1 = *(const float4*)(c + 4);
    d[j] = x0.x*a0.x + x0.y*a0.y + x0.z*a0.z + x0.w*a0.w
         + x1.x*a1.x + x1.y*a1.y + x1.z*a1.z + x1.w*a1.w;
  }
#pragma unroll
  for (int off = 32; off; off >>= 1)
#pragma unroll
    for (int j = 0; j < NCAND; ++j) d[j] += __shfl_xor(d[j], off);

  if (lane == 0) {
    u64 best = ~0ull;
#pragma unroll
    for (int j = 0; j < NCAND; ++j) {
      float s = cnh[idx[j]] - d[j];
      u64 key = ((u64)fsort(s) << 32) | (u32)idx[j];  // exact fp32 + np tie-break
      best = umin64(best, key);
    }
    out[wave] = (int)(u32)best;
  }
}

// ---------------------------------------------------------------- launch
extern "C" void kernel_launch(void* const* d_in, const int* in_sizes, int n_in,
                              void* d_out, int out_size, void* d_ws, size_t ws_size,
                              hipStream_t stream) {
  const float* x  = (const float*)d_in[0];
  const float* cb = (const float*)d_in[1];
  int* out = (int*)d_out;

  char* ws = (char*)d_ws;
  unsigned char* ch8  = (unsigned char*)(ws);
  unsigned char* xh8  = (unsigned char*)(ws + (size_t)4 * 1024 * 1024);
  float*         cnh  = (float*)(ws + (size_t)20 * 1024 * 1024);
  int*           cand = (int*)(ws + (size_t)20 * 1024 * 1024 + 32 * 1024);
  uint4*         part = (uint4*)(ws + (size_t)22 * 1024 * 1024);

  conv_codebook_kernel<<<KCODES / 4, 256, 0, stream>>>(cb, ch8, cnh);
  conv_x_kernel<<<(M_ROWS * DDIM) / (256 * 8), 256, 0, stream>>>(x, xh8);
  coarse_kernel<<<(M_ROWS / 128) * (KCODES / 128), 256, 0, stream>>>(xh8, ch8, cnh, part);
  merge_kernel<<<M_ROWS / 256, 256, 0, stream>>>(part, cand);
  rescore_kernel<<<M_ROWS / 4, 256, 0, stream>>>(x, cb, cnh, cand, out);
}

// Round 7
// 373.387 us; speedup vs baseline: 1.5468x; 1.0288x over previous
//
#include <hip/hip_runtime.h>
#include <hip/hip_bf16.h>
#include <hip/hip_fp16.h>

// Codebook argmin: x (32768,512) fp32, codebook (8192,512) fp32 -> codes (32768) int32
//
// v14: occupancy fix. v7/v8/v13 all sat at ~21.5% occupancy = 2 waves/SIMD:
// unified RF demand = 120 arch + 64 AGPR acc = ~184/wave -> every pipe
// (VALU/LDS/MFMA/staging) serialized per wave, chunk-slot ~4700cy vs 1104cy
// MFMA. v14 keeps the 128x128 block + LDS layout but splits it over 8 waves
// (512 thr, 2x4), wave-tile 64x32: acc[4][2]=32, af 32 + bf 16 -> total
// ~110 <= 128 -> 4 waves/SIMD (launch_bounds(512,4); LDS allows exactly 2
// blocks/CU = 16 waves). ds_read addressing hoisted to per-lane bases +
// immediate offsets. Epilogue: sorted-pair lanes, 4 wn passes, uint2 table.
//
// ws layout:
//   ch8  : fp8 [8192][512]   @ 0        (4 MB)
//   xh8  : fp8 [32768][512]  @ 4 MB     (16 MB)
//   cnh  : f32 [8192]        @ 20 MB    (32 KB)
//   cand : int [32768][8]    @ 20M+32K  (1 MB)
//   part : uint4 [64][32768] @ 22 MB    (16 MB)

#define M_ROWS 32768
#define DDIM   512
#define KCODES 8192
#define NCAND  8

typedef unsigned long long u64;
typedef unsigned int u32;
typedef __attribute__((ext_vector_type(4))) float f32x4;
typedef __attribute__((ext_vector_type(8))) int v8i;

#define GL2LDS(gp, lp) __builtin_amdgcn_global_load_lds(                  \
    (const __attribute__((address_space(1))) void*)(gp),                  \
    (__attribute__((address_space(3))) void*)(lp), 16, 0, 0)

__device__ __forceinline__ u32 umin32(u32 a, u32 b) { return a < b ? a : b; }
__device__ __forceinline__ u32 umax32(u32 a, u32 b) { return a > b ? a : b; }
__device__ __forceinline__ u64 umin64(u64 a, u64 b) { return a < b ? a : b; }
__device__ __forceinline__ u32 umin3(u32 a, u32 b, u32 c) {  // fuses to v_min3_u32
  return umin32(umin32(a, b), c);
}
__device__ __forceinline__ u32 med3u(u32 a, u32 b, u32 c) {
  u32 d;
  asm("v_med3_u32 %0, %1, %2, %3" : "=v"(d) : "v"(a), "v"(b), "v"(c));
  return d;
}

// float -> order-preserving u32 (ascending); used only in rescore
__device__ __forceinline__ u32 fsort(float s) {
  u32 fb = __float_as_uint(s);
  return fb ^ (u32)(((int)fb >> 31) | 0x80000000);
}

// 8 floats -> 8 packed e4m3 bytes (uint2)
__device__ __forceinline__ uint2 pk8_fp8(float4 v0, float4 v1) {
  int lo = 0, hi = 0;
  lo = __builtin_amdgcn_cvt_pk_fp8_f32(v0.x, v0.y, lo, false);
  lo = __builtin_amdgcn_cvt_pk_fp8_f32(v0.z, v0.w, lo, true);
  hi = __builtin_amdgcn_cvt_pk_fp8_f32(v1.x, v1.y, hi, false);
  hi = __builtin_amdgcn_cvt_pk_fp8_f32(v1.z, v1.w, hi, true);
  return (uint2){(u32)lo, (u32)hi};
}

// ---------------------------------------------------------------- conv codebook
__global__ __launch_bounds__(256) void conv_codebook_kernel(
    const float* __restrict__ cb, unsigned char* __restrict__ ch8,
    float* __restrict__ cnh) {
  int wave = (blockIdx.x * 256 + threadIdx.x) >> 6;
  int lane = threadIdx.x & 63;
  if (wave >= KCODES) return;
  const float* src = cb + (size_t)wave * DDIM + lane * 8;
  float4 v0 = *(const float4*)(src);
  float4 v1 = *(const float4*)(src + 4);
  *(uint2*)(ch8 + (size_t)wave * DDIM + lane * 8) = pk8_fp8(v0, v1);
  float ss = v0.x*v0.x + v0.y*v0.y + v0.z*v0.z + v0.w*v0.w
           + v1.x*v1.x + v1.y*v1.y + v1.z*v1.z + v1.w*v1.w;
#pragma unroll
  for (int off = 32; off; off >>= 1) ss += __shfl_xor(ss, off);
  if (lane == 0) cnh[wave] = 0.5f * ss;
}

// ---------------------------------------------------------------- conv x
__global__ __launch_bounds__(256) void conv_x_kernel(
    const float* __restrict__ x, unsigned char* __restrict__ xh8) {
  size_t i = ((size_t)blockIdx.x * 256 + threadIdx.x) * 8;
  float4 v0 = *(const float4*)(x + i);
  float4 v1 = *(const float4*)(x + i + 4);
  *(uint2*)(xh8 + i) = pk8_fp8(v0, v1);
}

// ---------------------------------------------------------------- coarse GEMM
// Block: 512 threads = 8 waves as 2x4 (wm,wn); wave = 64x32 outputs as 4x2
// grid of 16x16x128 scaled-fp8 MFMA (scales = 1.0 -> exact e4m3 math).
// K=512 in 4 chunks of BK=128 bytes, double-buffered, prefetch under MFMA.
// LDS[row][slot] = global[row][slot ^ (row&7)] (granule XOR swizzle).
__global__ __launch_bounds__(512, 4) void coarse_kernel(
    const unsigned char* __restrict__ xh8, const unsigned char* __restrict__ ch8,
    const float* __restrict__ cnh, uint4* __restrict__ part) {
  // 65536 B: 2 x {aL(16K)+bL(16K)}; epilogue tab uint2[128*17] (17.4 KB)
  // overlays buf0 (safe: first table write after post-loop barrier).
  __shared__ __align__(16) char smem[65536];
  uint2* tab = (uint2*)smem;

  const int tid  = threadIdx.x;
  const int lane = tid & 63;
  const int wid  = tid >> 6;
  const int wm   = wid >> 2, wn = wid & 3;   // 2 x 4 waves
  const int g    = lane >> 4, l16 = lane & 15;

  // XCD-band swizzle (neutral in v13, kept: harmless).
  const int xcd  = blockIdx.x & 7;
  const int lid  = blockIdx.x >> 3;
  const int nblk = lid >> 5;
  const int mblk = (xcd << 5) | (lid & 31);
  const int row0 = mblk * 128;
  const int col0 = nblk * 128;

  const int a_ = lane >> 3, b_ = lane & 7;
  // per-lane GL2LDS source: row +a_, granule b_^a_ of the current chunk
  const size_t gsrc = (size_t)a_ * DDIM + ((b_ ^ a_) << 4);
  const unsigned char* abase = xh8 + (size_t)row0 * DDIM + gsrc;
  const unsigned char* bbase = ch8 + (size_t)col0 * DDIM + gsrc;

  // per-lane LDS read geometry (shared by A and B: row&7 == l16&7):
  // fragment k-granules g*2, g*2+1 live at slots s0, s0^1 of the row.
  const int sl0 = (((g * 2) ^ (l16 & 7)) << 4);
  const int slX = sl0 ^ 16;
  const int aoff = (wm * 64 + l16) * 128;    // A frag t: + t*2048
  const int boff = (wn * 32 + l16) * 128;    // B frag tn: + tn*2048

// stage chunk cc (128 k-bytes of A and B tiles) into buffer `buf`:
// 32 GL2LDS per block (4 per wave: 2 A + 2 B)
#define STAGE(cc, buf) do {                                               \
    char* sa_ = smem + (buf) * 32768;                                     \
    _Pragma("unroll")                                                     \
    for (int j = 0; j < 2; ++j) {                                         \
      const int I_ = wid * 2 + j;                                         \
      const size_t off_ = (size_t)(I_ * 8) * DDIM + (size_t)(cc) * 128;   \
      GL2LDS(abase + off_, sa_ + I_ * 1024);                              \
      GL2LDS(bbase + off_, sa_ + 16384 + I_ * 1024);                      \
    }                                                                     \
  } while (0)

  // codes + half-norms for this wave's 32 columns; load early.
  u32 codev[2];
  float cn[2];
#pragma unroll
  for (int tn = 0; tn < 2; ++tn) {
    codev[tn] = (u32)(col0 + wn * 32 + tn * 16 + l16);
    cn[tn] = cnh[codev[tn]];
  }

  f32x4 acc[4][2];
#pragma unroll
  for (int tm = 0; tm < 4; ++tm)
#pragma unroll
    for (int tn = 0; tn < 2; ++tn) acc[tm][tn] = (f32x4){0.f, 0.f, 0.f, 0.f};

  STAGE(0, 0);
  __syncthreads();                           // drains vmcnt(0): buf0 ready

#pragma unroll
  for (int c = 0; c < 4; ++c) {              // K chunks of 128 bytes
    if (c < 3) STAGE(c + 1, (c + 1) & 1);    // prefetch: in flight under MFMAs
    const char* aL = smem + (c & 1) * 32768;
    const char* bL = aL + 16384;
    const char* paL = aL + aoff + sl0;
    const char* paH = aL + aoff + slX;
    const char* pbL = bL + boff + sl0;
    const char* pbH = bL + boff + slX;

    v8i af[4];
#pragma unroll
    for (int t = 0; t < 4; ++t) {
      int4 lo = *(const int4*)(paL + t * 2048);
      int4 hi = *(const int4*)(paH + t * 2048);
      af[t][0] = lo.x; af[t][1] = lo.y; af[t][2] = lo.z; af[t][3] = lo.w;
      af[t][4] = hi.x; af[t][5] = hi.y; af[t][6] = hi.z; af[t][7] = hi.w;
    }
#pragma unroll
    for (int tn = 0; tn < 2; ++tn) {
      int4 lo = *(const int4*)(pbL + tn * 2048);
      int4 hi = *(const int4*)(pbH + tn * 2048);
      v8i bf;
      bf[0] = lo.x; bf[1] = lo.y; bf[2] = lo.z; bf[3] = lo.w;
      bf[4] = hi.x; bf[5] = hi.y; bf[6] = hi.z; bf[7] = hi.w;
#pragma unroll
      for (int tm = 0; tm < 4; ++tm)
        acc[tm][tn] = __builtin_amdgcn_mfma_scale_f32_16x16x128_f8f6f4(
            af[tm], bf, acc[tm][tn],
            0, 0,                     // cbsz=fp8(e4m3), blgp=fp8(e4m3)
            0, 0x7F7F7F7F,            // opsel_a, scale_a = 1.0 (E8M0 127)
            0, 0x7F7F7F7F);           // opsel_b, scale_b = 1.0
    }
    __syncthreads();   // all reads of buf[c&1] done; buf[(c+1)&1] landed
  }

  // ---- epilogue phase 1: per-lane sorted pair over 2 cols x 16 rows ----
  // key = float_bits(s) & ~0x1FFF | code. s > 0 by 8-sigma margin.
  u32 k1[16], k2[16];
#pragma unroll
  for (int tm = 0; tm < 4; ++tm)
#pragma unroll
    for (int r = 0; r < 4; ++r) {
      const int sl = tm * 4 + r;
      float s0 = cn[0] - acc[tm][0][r];
      float s1 = cn[1] - acc[tm][1][r];
      u32 key0 = (__float_as_uint(s0) & 0xFFFFE000u) | codev[0];
      u32 key1 = (__float_as_uint(s1) & 0xFFFFE000u) | codev[1];
      k1[sl] = umin32(key0, key1);
      k2[sl] = umax32(key0, key1);
    }

  // ---- epilogue phase 2: LDS-table reduce, four wn passes ----
  // merge sorted {v.x<=v.y} into running sorted {m1<=m2<=m3}:
  //   a = max(m1,x); m1' = min(m1,x);
  //   b = med3(m2,a,y); m2' = min3(m2,a,y); m3' = min(m3,b).
  u32 m1 = ~0u, m2 = ~0u, m3 = ~0u;
#pragma unroll
  for (int p = 0; p < 4; ++p) {
    __syncthreads();
    if (wn == p) {
#pragma unroll
      for (int tm = 0; tm < 4; ++tm)
#pragma unroll
        for (int r = 0; r < 4; ++r) {
          const int row = wm * 64 + tm * 16 + g * 4 + r;
          const int sl = tm * 4 + r;
          tab[row * 17 + l16] = (uint2){k1[sl], k2[sl]};
        }
    }
    __syncthreads();
    if (tid < 128) {
#pragma unroll
      for (int e = 0; e < 16; ++e) {
        uint2 v = tab[tid * 17 + e];
        u32 a = umax32(m1, v.x);
        m1 = umin32(m1, v.x);
        u32 b = med3u(m2, a, v.y);
        m2 = umin3(m2, a, v.y);
        m3 = umin32(m3, b);
      }
    }
  }

  if (tid < 128)
    part[(size_t)nblk * M_ROWS + row0 + tid] = (uint4){m1, m2, m3, 0u};
#undef STAGE
}

// ---------------------------------------------------------------- merge: global top-8
__global__ __launch_bounds__(256) void merge_kernel(
    const uint4* __restrict__ part, int* __restrict__ cand) {
  const int row = blockIdx.x * 256 + threadIdx.x;
  u32 k[NCAND];
#pragma unroll
  for (int i = 0; i < NCAND; ++i) k[i] = ~0u;
  for (int nb = 0; nb < KCODES / 128; ++nb) {
    uint4 e = part[(size_t)nb * M_ROWS + row];
    u32 t = e.x;
#pragma unroll
    for (int i = 0; i < NCAND; ++i) { u32 mx = umax32(k[i], t); k[i] = umin32(k[i], t); t = mx; }
    t = e.y;
#pragma unroll
    for (int i = 0; i < NCAND; ++i) { u32 mx = umax32(k[i], t); k[i] = umin32(k[i], t); t = mx; }
    t = e.z;
#pragma unroll
    for (int i = 0; i < NCAND; ++i) { u32 mx = umax32(k[i], t); k[i] = umin32(k[i], t); t = mx; }
  }
#pragma unroll
  for (int i = 0; i < NCAND; ++i)
    cand[row * NCAND + i] = (int)(k[i] & 0x1FFFu);
}

// ---------------------------------------------------------------- fp32 rescore (8)
__global__ __launch_bounds__(256) void rescore_kernel(
    const float* __restrict__ x, const float* __restrict__ cb,
    const float* __restrict__ cnh, const int* __restrict__ cand,
    int* __restrict__ out) {
  int wave = (blockIdx.x * 256 + threadIdx.x) >> 6;
  int lane = threadIdx.x & 63;
  if (wave >= M_ROWS) return;
  int idx[NCAND];
#pragma unroll
  for (int j = 0; j < NCAND; ++j) idx[j] = cand[wave * NCAND + j];

  const float* xr = x + (size_t)wave * DDIM + lane * 8;
  float4 x0 = *(const float4*)(xr);
  float4 x1 = *(const float4*)(xr + 4);

  float d[NCAND];
#pragma unroll
  for (int j = 0; j < NCAND; ++j) {
    const float* c = cb + (size_t)idx[j] * DDIM + lane * 8;
    float4 a0 = *(const float4*)(c);
    float4 a1 = *(const float4*)(c + 4);
    d[j] = x0.x*a0.x + x0.y*a0.y + x0.z*a0.z + x0.w*a0.w
         + x1.x*a1.x + x1.y*a1.y + x1.z*a1.z + x1.w*a1.w;
  }
#pragma unroll
  for (int off = 32; off; off >>= 1)
#pragma unroll
    for (int j = 0; j < NCAND; ++j) d[j] += __shfl_xor(d[j], off);

  if (lane == 0) {
    u64 best = ~0ull;
#pragma unroll
    for (int j = 0; j < NCAND; ++j) {
      float s = cnh[idx[j]] - d[j];
      u64 key = ((u64)fsort(s) << 32) | (u32)idx[j];  // exact fp32 + np tie-break
      best = umin64(best, key);
    }
    out[wave] = (int)(u32)best;
  }
}

// ---------------------------------------------------------------- launch
extern "C" void kernel_launch(void* const* d_in, const int* in_sizes, int n_in,
                              void* d_out, int out_size, void* d_ws, size_t ws_size,
                              hipStream_t stream) {
  const float* x  = (const float*)d_in[0];
  const float* cb = (const float*)d_in[1];
  int* out = (int*)d_out;

  char* ws = (char*)d_ws;
  unsigned char* ch8  = (unsigned char*)(ws);
  unsigned char* xh8  = (unsigned char*)(ws + (size_t)4 * 1024 * 1024);
  float*         cnh  = (float*)(ws + (size_t)20 * 1024 * 1024);
  int*           cand = (int*)(ws + (size_t)20 * 1024 * 1024 + 32 * 1024);
  uint4*         part = (uint4*)(ws + (size_t)22 * 1024 * 1024);

  conv_codebook_kernel<<<KCODES / 4, 256, 0, stream>>>(cb, ch8, cnh);
  conv_x_kernel<<<(M_ROWS * DDIM) / (256 * 8), 256, 0, stream>>>(x, xh8);
  coarse_kernel<<<(M_ROWS / 128) * (KCODES / 128), 512, 0, stream>>>(xh8, ch8, cnh, part);
  merge_kernel<<<M_ROWS / 256, 256, 0, stream>>>(part, cand);
  rescore_kernel<<<M_ROWS / 4, 256, 0, stream>>>(x, cb, cnh, cand, out);
}

// Round 8
// 367.734 us; speedup vs baseline: 1.5706x; 1.0154x over previous
//
#include <hip/hip_runtime.h>
#include <hip/hip_bf16.h>
#include <hip/hip_fp16.h>

// Codebook argmin: x (32768,512) fp32, codebook (8192,512) fp32 -> codes (32768) int32
//
// v15: A-in-registers coarse pass. v14 proved the wall is the LDS pipe
// (reads 164us + writes 27us of the 246us; MFMA only 59us). Fix: block is
// persistent over a 1024-col strip; each wave holds its A rows (32 x K512
// = 64 VGPR) loaded ONCE from global (L2/L3), only B streams through LDS
// (8KB chunk dbuf, 1 GL2LDS/thread/chunk). LDS-read per chunk-block drops
// 96 -> 32 b128 (-67%). Block = 512 thr = 8 waves (4 wm x 2 wn), wave tile
// 32x32, 16 steps of 64 cols. Epilogue: lazy keys -> uint2 tab (2 passes),
// reducer threads (tid<128) keep running top-3 across 4 steps -> part =
// top-3 per 256-col slice (32 slices, v9-verified granularity).
//
// ws layout:
//   ch8  : fp8 [8192][512]   @ 0        (4 MB)
//   xh8  : fp8 [32768][512]  @ 4 MB     (16 MB)
//   cnh  : f32 [8192]        @ 20 MB    (32 KB)
//   cand : int [32768][8]    @ 20M+32K  (1 MB)
//   part : uint4 [32][32768] @ 22 MB    (16 MB)

#define M_ROWS 32768
#define DDIM   512
#define KCODES 8192
#define NCAND  8

typedef unsigned long long u64;
typedef unsigned int u32;
typedef __attribute__((ext_vector_type(4))) float f32x4;
typedef __attribute__((ext_vector_type(8))) int v8i;

#define GL2LDS(gp, lp) __builtin_amdgcn_global_load_lds(                  \
    (const __attribute__((address_space(1))) void*)(gp),                  \
    (__attribute__((address_space(3))) void*)(lp), 16, 0, 0)

__device__ __forceinline__ u32 umin32(u32 a, u32 b) { return a < b ? a : b; }
__device__ __forceinline__ u32 umax32(u32 a, u32 b) { return a > b ? a : b; }
__device__ __forceinline__ u64 umin64(u64 a, u64 b) { return a < b ? a : b; }
__device__ __forceinline__ u32 umin3(u32 a, u32 b, u32 c) {  // fuses to v_min3_u32
  return umin32(umin32(a, b), c);
}
__device__ __forceinline__ u32 med3u(u32 a, u32 b, u32 c) {
  u32 d;
  asm("v_med3_u32 %0, %1, %2, %3" : "=v"(d) : "v"(a), "v"(b), "v"(c));
  return d;
}

// float -> order-preserving u32 (ascending); used only in rescore
__device__ __forceinline__ u32 fsort(float s) {
  u32 fb = __float_as_uint(s);
  return fb ^ (u32)(((int)fb >> 31) | 0x80000000);
}

// 8 floats -> 8 packed e4m3 bytes (uint2)
__device__ __forceinline__ uint2 pk8_fp8(float4 v0, float4 v1) {
  int lo = 0, hi = 0;
  lo = __builtin_amdgcn_cvt_pk_fp8_f32(v0.x, v0.y, lo, false);
  lo = __builtin_amdgcn_cvt_pk_fp8_f32(v0.z, v0.w, lo, true);
  hi = __builtin_amdgcn_cvt_pk_fp8_f32(v1.x, v1.y, hi, false);
  hi = __builtin_amdgcn_cvt_pk_fp8_f32(v1.z, v1.w, hi, true);
  return (uint2){(u32)lo, (u32)hi};
}

// ---------------------------------------------------------------- conv codebook
__global__ __launch_bounds__(256) void conv_codebook_kernel(
    const float* __restrict__ cb, unsigned char* __restrict__ ch8,
    float* __restrict__ cnh) {
  int wave = (blockIdx.x * 256 + threadIdx.x) >> 6;
  int lane = threadIdx.x & 63;
  if (wave >= KCODES) return;
  const float* src = cb + (size_t)wave * DDIM + lane * 8;
  float4 v0 = *(const float4*)(src);
  float4 v1 = *(const float4*)(src + 4);
  *(uint2*)(ch8 + (size_t)wave * DDIM + lane * 8) = pk8_fp8(v0, v1);
  float ss = v0.x*v0.x + v0.y*v0.y + v0.z*v0.z + v0.w*v0.w
           + v1.x*v1.x + v1.y*v1.y + v1.z*v1.z + v1.w*v1.w;
#pragma unroll
  for (int off = 32; off; off >>= 1) ss += __shfl_xor(ss, off);
  if (lane == 0) cnh[wave] = 0.5f * ss;
}

// ---------------------------------------------------------------- conv x
__global__ __launch_bounds__(256) void conv_x_kernel(
    const float* __restrict__ x, unsigned char* __restrict__ xh8) {
  size_t i = ((size_t)blockIdx.x * 256 + threadIdx.x) * 8;
  float4 v0 = *(const float4*)(x + i);
  float4 v1 = *(const float4*)(x + i + 4);
  *(uint2*)(xh8 + i) = pk8_fp8(v0, v1);
}

// ---------------------------------------------------------------- coarse GEMM
// Block: 512 thr = 8 waves as 4x2 (wm,wn); wave tile 32 rows x 32 cols as
// 2x2 grid of 16x16x128 scaled-fp8 MFMA (scales=1.0 -> exact e4m3 math).
// A (32 rows x K512 per wave) lives in 64 VGPRs, loaded once from global.
// B: 16 steps of 64 cols; per step K=512 in 4 chunks of 8KB staged via
// GL2LDS (1 inst/thread), double-buffered (buffer parity = c&1).
// LDS[code][slot] = global[code][slot ^ (code&7)] (granule XOR swizzle).
__global__ __launch_bounds__(512, 4) void coarse_kernel(
    const unsigned char* __restrict__ xh8, const unsigned char* __restrict__ ch8,
    const float* __restrict__ cnh, uint4* __restrict__ part) {
  // B dbuf 2x8KB @0; tab uint2[128*17] (17408 B) @16384. Total 33792 B
  // -> 4 blocks/CU (LDS), 32 waves/CU possible.
  __shared__ __align__(16) char smem[33792];
  uint2* tab = (uint2*)(smem + 16384);

  const int tid  = threadIdx.x;
  const int lane = tid & 63;
  const int wid  = tid >> 6;
  const int wm   = wid >> 1, wn = wid & 1;   // 4 x 2 waves
  const int g    = lane >> 4, l16 = lane & 15;

  // blockIdx = mblk*8 + ngrp: dispatch round-robin puts ngrp==XCD ->
  // each XCD keeps one 1024-col B panel (512 KB) L2-resident.
  const int mblk = blockIdx.x >> 3;
  const int ngrp = blockIdx.x & 7;
  const int row0 = mblk * 128;
  const int colgrp = ngrp * 1024;

  // ---- A in registers: rows row0 + wm*32 + tm*16 + l16, full K ----
  // A[tm][c] = granules g*2, g*2+1 of chunk c (straight from global, no
  // swizzle needed: per-lane 2x16B loads).
  v8i A[2][4];
#pragma unroll
  for (int tm = 0; tm < 2; ++tm) {
    const unsigned char* ap =
        xh8 + (size_t)(row0 + wm * 32 + tm * 16 + l16) * DDIM + g * 32;
#pragma unroll
    for (int c = 0; c < 4; ++c) {
      int4 lo = *(const int4*)(ap + c * 128);
      int4 hi = *(const int4*)(ap + c * 128 + 16);
      A[tm][c][0] = lo.x; A[tm][c][1] = lo.y; A[tm][c][2] = lo.z; A[tm][c][3] = lo.w;
      A[tm][c][4] = hi.x; A[tm][c][5] = hi.y; A[tm][c][6] = hi.z; A[tm][c][7] = hi.w;
    }
  }

  // ---- B staging geometry: thread -> (code, granule) ----
  const int scode = tid >> 3;                       // 0..63
  const int sgran = (tid & 7) ^ (scode & 7);        // XOR swizzle
  const unsigned char* bsrc =
      ch8 + (size_t)(colgrp + scode) * DDIM + sgran * 16;
  // LDS dest is linear: smem + buf*8192 + tid*16  -> LDS[code][tid&7].

  // ---- per-lane B read offsets (constant): row = wn*32 + tn*16 + l16 ----
  const int brow = wn * 32 + l16;                   // tn=0 row
  const int bsl  = ((g * 2) ^ (l16 & 7)) << 4;
  const int boff = brow * 128 + bsl;                // tn=1: +2048

  // running top-3 for the 256-col slice (reducer threads tid<128)
  u32 m1 = ~0u, m2 = ~0u, m3 = ~0u;

  // prologue: stage (nb=0, c=0) into buf0
  GL2LDS(bsrc, smem + tid * 16);
  __syncthreads();

  for (int nb = 0; nb < 16; ++nb) {                 // 16 steps of 64 cols
    const int col0 = colgrp + nb * 64;
    u32 codev[2];
    float cn[2];
#pragma unroll
    for (int tn = 0; tn < 2; ++tn) {
      codev[tn] = (u32)(col0 + wn * 32 + tn * 16 + l16);
      cn[tn] = cnh[codev[tn]];
    }

    f32x4 acc[2][2];
#pragma unroll
    for (int tm = 0; tm < 2; ++tm)
#pragma unroll
      for (int tn = 0; tn < 2; ++tn) acc[tm][tn] = (f32x4){0.f, 0.f, 0.f, 0.f};

#pragma unroll
    for (int c = 0; c < 4; ++c) {                   // K chunks of 128 B
      // prefetch next chunk (next step's chunk0 when c==3)
      if (c < 3)
        GL2LDS(bsrc + (c + 1) * 128, smem + ((c + 1) & 1) * 8192 + tid * 16);
      else if (nb < 15)
        GL2LDS(bsrc + 32768, smem + tid * 16);      // buf0 = (3+1)&1

      const char* bL = smem + (c & 1) * 8192;
#pragma unroll
      for (int tn = 0; tn < 2; ++tn) {
        int4 lo = *(const int4*)(bL + boff + tn * 2048);
        int4 hi = *(const int4*)(bL + ((boff + tn * 2048) ^ 16));
        v8i bf;
        bf[0] = lo.x; bf[1] = lo.y; bf[2] = lo.z; bf[3] = lo.w;
        bf[4] = hi.x; bf[5] = hi.y; bf[6] = hi.z; bf[7] = hi.w;
#pragma unroll
        for (int tm = 0; tm < 2; ++tm)
          acc[tm][tn] = __builtin_amdgcn_mfma_scale_f32_16x16x128_f8f6f4(
              A[tm][c], bf, acc[tm][tn],
              0, 0,                     // cbsz=fp8(e4m3), blgp=fp8(e4m3)
              0, 0x7F7F7F7F,            // opsel_a, scale_a = 1.0 (E8M0 127)
              0, 0x7F7F7F7F);           // opsel_b, scale_b = 1.0
      }
      __syncthreads();   // staged buf ready AND all reads of buf[c&1] done
    }

    // ---- step epilogue: lazy keys -> uint2 tab, 2 wn passes ----
    // key = float_bits(s) & ~0x1FFF | code (s > 0 by 8-sigma margin).
    // Reducer merges sorted pair {x<=y} into running {m1<=m2<=m3}:
    //   a = max(m1,x); m1' = min(m1,x);
    //   b = med3(m2,a,y); m2' = min3(m2,a,y); m3' = min(m3,b).
#pragma unroll
    for (int p = 0; p < 2; ++p) {
      if (wn == p) {
#pragma unroll
        for (int tm = 0; tm < 2; ++tm)
#pragma unroll
          for (int r = 0; r < 4; ++r) {
            float s0 = cn[0] - acc[tm][0][r];
            float s1 = cn[1] - acc[tm][1][r];
            u32 key0 = (__float_as_uint(s0) & 0xFFFFE000u) | codev[0];
            u32 key1 = (__float_as_uint(s1) & 0xFFFFE000u) | codev[1];
            const int row = wm * 32 + tm * 16 + g * 4 + r;
            tab[row * 17 + l16] = (uint2){umin32(key0, key1), umax32(key0, key1)};
          }
      }
      __syncthreads();
      if (tid < 128) {
#pragma unroll
        for (int e = 0; e < 16; ++e) {
          uint2 v = tab[tid * 17 + e];
          u32 a = umax32(m1, v.x);
          m1 = umin32(m1, v.x);
          u32 b = med3u(m2, a, v.y);
          m2 = umin3(m2, a, v.y);
          m3 = umin32(m3, b);
        }
      }
      __syncthreads();   // tab consumed; next pass (or next step) may write
    }

    if ((nb & 3) == 3) {                            // end of 256-col slice
      if (tid < 128) {
        part[(size_t)(ngrp * 4 + (nb >> 2)) * M_ROWS + row0 + tid] =
            (uint4){m1, m2, m3, 0u};
        m1 = ~0u; m2 = ~0u; m3 = ~0u;
      }
    }
    bsrc += 32768;                                  // next 64-col step
  }
}

// ---------------------------------------------------------------- merge: global top-8
__global__ __launch_bounds__(256) void merge_kernel(
    const uint4* __restrict__ part, int* __restrict__ cand) {
  const int row = blockIdx.x * 256 + threadIdx.x;
  u32 k[NCAND];
#pragma unroll
  for (int i = 0; i < NCAND; ++i) k[i] = ~0u;
  for (int nb = 0; nb < KCODES / 256; ++nb) {
    uint4 e = part[(size_t)nb * M_ROWS + row];
    u32 t = e.x;
#pragma unroll
    for (int i = 0; i < NCAND; ++i) { u32 mx = umax32(k[i], t); k[i] = umin32(k[i], t); t = mx; }
    t = e.y;
#pragma unroll
    for (int i = 0; i < NCAND; ++i) { u32 mx = umax32(k[i], t); k[i] = umin32(k[i], t); t = mx; }
    t = e.z;
#pragma unroll
    for (int i = 0; i < NCAND; ++i) { u32 mx = umax32(k[i], t); k[i] = umin32(k[i], t); t = mx; }
  }
#pragma unroll
  for (int i = 0; i < NCAND; ++i)
    cand[row * NCAND + i] = (int)(k[i] & 0x1FFFu);
}

// ---------------------------------------------------------------- fp32 rescore (8)
__global__ __launch_bounds__(256) void rescore_kernel(
    const float* __restrict__ x, const float* __restrict__ cb,
    const float* __restrict__ cnh, const int* __restrict__ cand,
    int* __restrict__ out) {
  int wave = (blockIdx.x * 256 + threadIdx.x) >> 6;
  int lane = threadIdx.x & 63;
  if (wave >= M_ROWS) return;
  int idx[NCAND];
#pragma unroll
  for (int j = 0; j < NCAND; ++j) idx[j] = cand[wave * NCAND + j];

  const float* xr = x + (size_t)wave * DDIM + lane * 8;
  float4 x0 = *(const float4*)(xr);
  float4 x1 = *(const float4*)(xr + 4);

  float d[NCAND];
#pragma unroll
  for (int j = 0; j < NCAND; ++j) {
    const float* c = cb + (size_t)idx[j] * DDIM + lane * 8;
    float4 a0 = *(const float4*)(c);
    float4 a1 = *(const float4*)(c + 4);
    d[j] = x0.x*a0.x + x0.y*a0.y + x0.z*a0.z + x0.w*a0.w
         + x1.x*a1.x + x1.y*a1.y + x1.z*a1.z + x1.w*a1.w;
  }
#pragma unroll
  for (int off = 32; off; off >>= 1)
#pragma unroll
    for (int j = 0; j < NCAND; ++j) d[j] += __shfl_xor(d[j], off);

  if (lane == 0) {
    u64 best = ~0ull;
#pragma unroll
    for (int j = 0; j < NCAND; ++j) {
      float s = cnh[idx[j]] - d[j];
      u64 key = ((u64)fsort(s) << 32) | (u32)idx[j];  // exact fp32 + np tie-break
      best = umin64(best, key);
    }
    out[wave] = (int)(u32)best;
  }
}

// ---------------------------------------------------------------- launch
extern "C" void kernel_launch(void* const* d_in, const int* in_sizes, int n_in,
                              void* d_out, int out_size, void* d_ws, size_t ws_size,
                              hipStream_t stream) {
  const float* x  = (const float*)d_in[0];
  const float* cb = (const float*)d_in[1];
  int* out = (int*)d_out;

  char* ws = (char*)d_ws;
  unsigned char* ch8  = (unsigned char*)(ws);
  unsigned char* xh8  = (unsigned char*)(ws + (size_t)4 * 1024 * 1024);
  float*         cnh  = (float*)(ws + (size_t)20 * 1024 * 1024);
  int*           cand = (int*)(ws + (size_t)20 * 1024 * 1024 + 32 * 1024);
  uint4*         part = (uint4*)(ws + (size_t)22 * 1024 * 1024);

  conv_codebook_kernel<<<KCODES / 4, 256, 0, stream>>>(cb, ch8, cnh);
  conv_x_kernel<<<(M_ROWS * DDIM) / (256 * 8), 256, 0, stream>>>(x, xh8);
  coarse_kernel<<<(M_ROWS / 128) * 8, 512, 0, stream>>>(xh8, ch8, cnh, part);
  merge_kernel<<<M_ROWS / 256, 256, 0, stream>>>(part, cand);
  rescore_kernel<<<M_ROWS / 4, 256, 0, stream>>>(x, cb, cnh, cand, out);
}